// Round 11
// baseline (272.699 us; speedup 1.0000x reference)
//
#include <hip/hip_runtime.h>

typedef __bf16 bf16;
typedef __attribute__((ext_vector_type(8))) __bf16 bf16x8;
typedef __attribute__((ext_vector_type(4))) __bf16 bf16x4;
typedef __attribute__((ext_vector_type(4))) float f32x4;

#define B_    64
#define N_    197
#define C_    768
#define H_    12
#define HD_   64
#define SCALE_ 0.125f
#define NM_   (N_*N_)         // 38809
#define M_    (B_*N_)         // 12608
#define VTP_  200             // vbufT row pad
#define RPT_  208             // rpbT row stride (cols 197..207 pre-poisoned to -30000)

#define GLL16(gptr, lptr) \
  __builtin_amdgcn_global_load_lds((const __attribute__((address_space(1))) unsigned int*)(gptr), \
                                   (__attribute__((address_space(3))) unsigned int*)(lptr), 16, 0, 0)

// ---------------- fused prep: cast x/proj_w, W_eff + bias, rpbT ----------------
// blocks [0,5016): cast; [5016,11928): weff; [11928,13849): rpbT
// rpbT layout [h][q-row n][k-col m], stride RPT_=208: cols [197,208) filled with
// -30000 so attn's QK loop needs NO column mask (exp underflows to exact 0).
__global__ __launch_bounds__(256) void prep_kernel(
    const float* __restrict__ x, const float* __restrict__ pw,
    const float* __restrict__ qkv_w, const float* __restrict__ q_bias, const float* __restrict__ v_bias,
    const float* __restrict__ qa, const float* __restrict__ qb,
    const float* __restrict__ ka, const float* __restrict__ kb,
    const float* __restrict__ va, const float* __restrict__ vb,
    const float* __restrict__ table, const int* __restrict__ rpi,
    bf16* __restrict__ xbf, bf16* __restrict__ pwbf,
    bf16* __restrict__ weff, float* __restrict__ biasf, bf16* __restrict__ rpbT)
{
  const int bid = blockIdx.x, tid = threadIdx.x;
  if (bid < 5016) {
    const size_t n1 = (size_t)M_ * C_;   // 9,682,944
    size_t i8 = ((size_t)bid * 256 + tid) * 8;
    const float* src; bf16* dst; size_t off;
    if (i8 < n1) { src = x;  dst = xbf;  off = i8; }
    else         { src = pw; dst = pwbf; off = i8 - n1; }
    float4 f0 = *(const float4*)(src + off);
    float4 f1 = *(const float4*)(src + off + 4);
    bf16x8 v8;
    v8[0] = (bf16)f0.x; v8[1] = (bf16)f0.y; v8[2] = (bf16)f0.z; v8[3] = (bf16)f0.w;
    v8[4] = (bf16)f1.x; v8[5] = (bf16)f1.y; v8[6] = (bf16)f1.z; v8[7] = (bf16)f1.w;
    *(bf16x8*)(dst + off) = v8;
  } else if (bid < 11928) {
    int idx = (bid - 5016) * 256 + tid;          // < 1,769,472 exact
    int d = idx / C_, c = idx - d * C_;
    int sel = d / C_, dd = d - sel * C_;
    const float* a  = (sel == 0) ? qa : (sel == 1) ? ka : va;
    const float* bw = (sel == 0) ? qb : (sel == 1) ? kb : vb;
    float acc = qkv_w[idx];
#pragma unroll
    for (int r = 0; r < 24; ++r)
      acc += bw[dd * 24 + r] * a[r * C_ + c];
    weff[idx] = (bf16)acc;
    if (c == 0)
      biasf[d] = (sel == 0) ? q_bias[dd] : (sel == 2) ? v_bias[dd] : 0.0f;
  } else {
    int idx = (bid - 11928) * 256 + tid;
    if (idx < H_ * N_ * RPT_) {
      int h = idx / (N_ * RPT_), rem = idx - h * (N_ * RPT_);
      int n = rem / RPT_, m = rem - n * RPT_;
      float v = (m < N_) ? table[rpi[n * N_ + m] * H_ + h] : -30000.0f;
      rpbT[((size_t)h * N_ + n) * RPT_ + m] = (bf16)v;   // unit-stride write
    }
  }
}

// ---------------- gemm_bt: C[M,Nn] = A[M,K] @ B[Nn,K]^T, bf16 operands ----------------
// R10 winner, UNTOUCHED: BM=128, 8 waves, 32KB LDS, 32 waves/CU, packed bf16x4 v-stores,
// m204 bijective XCD-chunked swizzle. R10 counters: FETCH 97->43MB, time flat ->
// structure-bound at this occupancy; leave alone.
// MODE 0: scatter q(xSCALE)/k -> [B,H,N,HD]; v -> TRANSPOSED [B,H,HD,VTP_]
// MODE 1: C[m,d] = acc + biasp[d] -> f32 out
template<int MODE, int BM>
__global__ __launch_bounds__(512, 8) void gemm_bt(
    const bf16* __restrict__ A, const bf16* __restrict__ Bw,
    const float* __restrict__ biasp,
    float* __restrict__ Coutf, int M, int Nn, int K,
    bf16* __restrict__ qo, bf16* __restrict__ ko, bf16* __restrict__ vo)
{
  __shared__ __align__(16) bf16 As[BM * 64];
  __shared__ __align__(16) bf16 Bs[128 * 64];
  const int tid = threadIdx.x;
  const int lane = tid & 63, w = tid >> 6;          // 8 waves
  const int l15 = lane & 15, quad = lane >> 4;
  const int wm = (w & 1) * 64;                      // M half (64 rows)
  const int wn = (w >> 1) * 32;                     // N quarter (32 cols)
  constexpr int NF = 2;                             // B-fragments per wave

  // m204 bijective XCD-chunked swizzle
  const int ntx = gridDim.x;
  const int nwg = ntx * gridDim.y;
  const int orig = blockIdx.y * ntx + blockIdx.x;
  const int xcd = orig & 7, hi = orig >> 3;
  const int qq = nwg >> 3, rr = nwg & 7;
  const int wg = (xcd < rr ? xcd * (qq + 1) : rr * (qq + 1) + (xcd - rr) * qq) + hi;
  const int rowB0 = (wg % ntx) * 128;   // N-tile (fastest-varying)
  const int rowA0 = (wg / ntx) * BM;    // M-tile

  f32x4 acc[4][NF] = {};

  for (int kt = 0; kt < K; kt += 64) {
#pragma unroll
    for (int i = 0; i < BM / 64; ++i) {            // A: BM x 64 tile
      int lin = i * 512 + tid;
      int r  = lin >> 3;                           // 0..BM-1
      int cb = lin & 7;                            // LDS column block
      int csw = ((cb ^ (r & 7)) << 3);             // swizzled global column (elems)
      int ga = rowA0 + r; if (ga > M - 1) ga = M - 1;
      GLL16(A + (size_t)ga * K + kt + csw, &As[lin * 8]);
    }
#pragma unroll
    for (int i = 0; i < 2; ++i) {                  // B: 128 x 64 tile
      int lin = i * 512 + tid;
      int r  = lin >> 3;
      int cb = lin & 7;
      int csw = ((cb ^ (r & 7)) << 3);
      int gb = rowB0 + r; if (gb > Nn - 1) gb = Nn - 1;
      GLL16(Bw + (size_t)gb * K + kt + csw, &Bs[lin * 8]);
    }
    __syncthreads();
#pragma unroll
    for (int ks = 0; ks < 2; ++ks) {
      const int cb = ks * 4 + quad;                // k-block 0..7
      const int sw = (cb ^ (l15 & 7)) << 3;
      bf16x8 af[4], bfr[NF];
#pragma unroll
      for (int i = 0; i < 4; ++i)
        af[i] = *(const bf16x8*)(&As[(wm + i * 16 + l15) * 64 + sw]);
#pragma unroll
      for (int j = 0; j < NF; ++j)
        bfr[j] = *(const bf16x8*)(&Bs[(wn + j * 16 + l15) * 64 + sw]);
#pragma unroll
      for (int i = 0; i < 4; ++i)
#pragma unroll
        for (int j = 0; j < NF; ++j)
          acc[i][j] = __builtin_amdgcn_mfma_f32_16x16x32_bf16(af[i], bfr[j], acc[i][j], 0, 0, 0);
    }
    __syncthreads();
  }

#pragma unroll
  for (int i = 0; i < 4; ++i) {
#pragma unroll
    for (int j = 0; j < NF; ++j) {
      const int m0 = rowA0 + wm + i * 16 + quad * 4;
      const int d  = rowB0 + wn + j * 16 + l15;
      const float bias = biasp[d];
      if (MODE == 0) {
        const int sel = d / C_, dd = d - sel * C_;
        const int h = dd >> 6, hd = dd & 63;
        if (sel == 2) {
          // v transposed: lane's 4 r-values = consecutive n for fixed (b,h,hd) row
          int b0 = m0 / N_, n0 = m0 - b0 * N_;
          if (m0 + 3 < M && n0 + 3 < N_) {
            bf16x4 pv;
#pragma unroll
            for (int r = 0; r < 4; ++r) pv[r] = (bf16)(acc[i][j][r] + bias);
            *(bf16x4*)(vo + (((size_t)b0 * H_ + h) * HD_ + hd) * VTP_ + n0) = pv;
          } else {
#pragma unroll
            for (int r = 0; r < 4; ++r) {
              int m = m0 + r; if (m >= M) continue;
              int b = m / N_, n = m - b * N_;
              vo[(((size_t)b * H_ + h) * HD_ + hd) * VTP_ + n] = (bf16)(acc[i][j][r] + bias);
            }
          }
        } else {
#pragma unroll
          for (int r = 0; r < 4; ++r) {
            int m = m0 + r; if (m >= M) continue;
            int b = m / N_, n = m - b * N_;
            float v = acc[i][j][r] + bias;
            if (sel == 0)
              qo[(((size_t)b * H_ + h) * N_ + n) * HD_ + hd] = (bf16)(v * SCALE_);
            else
              ko[(((size_t)b * H_ + h) * N_ + n) * HD_ + hd] = (bf16)v;
          }
        }
      } else {
#pragma unroll
        for (int r = 0; r < 4; ++r) {
          int m = m0 + r; if (m >= M) continue;
          Coutf[(size_t)m * Nn + d] = acc[i][j][r] + bias;
        }
      }
    }
  }
}

// ---------------- attention: barrier-free, max-free softmax, interleaved QK/PV ----------------
// R11 (attn was flat through 3 memory fixes + interleave -> occupancy/VALU-chain bound):
// 1) SW 232->208: LDS 29696->26624 B -> 6 blocks/CU (24 wave slots, +20% vs 20).
//    Lost zero-pad cols [208,224) handled by PV tail: A-frag for quad>=2 replaced by
//    exact 0 (4 cndmask); cols 197..207 are exact 0 in LDS (exp(-30000)) so all
//    garbage-V products vanish. Identical math.
// 2) Maskless QK: rpbT stride RPT_=208 with cols [197,208) pre-poisoned to -30000 by
//    prep -> sv = s[r]+rbv[r] unconditionally; row clamp hoisted out of the loop.
//    Removes ~104 VALU ops/wave from the hot chain.
#define SW 208   // P row stride (bf16 elems); PV consumes cols 0..207
__global__ __launch_bounds__(256) void attn_kernel(
    const bf16* __restrict__ q, const bf16* __restrict__ k, const bf16* __restrict__ vT_g,
    const bf16* __restrict__ rpbT, bf16* __restrict__ out)
{
  __shared__ __align__(16) bf16 s_lds[64 * SW];   // P tile (each wave owns its 16 rows)

  const int tid = threadIdx.x;
  const int lane = tid & 63, w = tid >> 6;
  const int l15 = lane & 15, quad = lane >> 4;
  // XCD-chunked bijection (3072 = 8 XCDs x 384): same-(h,b) blocks co-located.
  const int lid = blockIdx.x;
  const int wg = (lid & 7) * 384 + (lid >> 3);
  const int qt = wg & 3;
  const int hb = wg >> 2;
  const int h = hb % H_;
  const int b = hb / H_;
  const size_t bh = ((size_t)b * H_ + h) * N_ * HD_;
  const bf16* qb = q + bh;
  const bf16* kb = k + bh;
  const bf16* vg = vT_g + ((size_t)b * H_ + h) * HD_ * VTP_;

  const int row0 = qt * 64 + w * 16;
  int qm = row0 + l15; if (qm > N_ - 1) qm = N_ - 1;
  bf16x8 aq0 = *(const bf16x8*)(qb + qm * HD_ + quad * 8);
  bf16x8 aq1 = *(const bf16x8*)(qb + qm * HD_ + 32 + quad * 8);

  // hoisted row indices for rpbT (clamped; dead rows' outputs discarded at store)
  int rn4[4];
#pragma unroll
  for (int r2 = 0; r2 < 4; ++r2) {
    int rn = row0 + quad * 4 + r2; if (rn > N_ - 1) rn = N_ - 1;
    rn4[r2] = rn;
  }

  // 2-deep K pipeline: slot jt&1 computes, slot (jt+1)&1 prefetches
  bf16x8 pk0[2], pk1[2];
  {
    const bf16* kp0 = kb + l15 * HD_ + quad * 8;   // jt=0: kn = l15 (<197, no clamp)
    pk0[0] = *(const bf16x8*)(kp0);
    pk1[0] = *(const bf16x8*)(kp0 + 32);
  }
  // 1-deep V: fragments for current kk (loads fly under the 2 preceding QK iters)
  bf16x8 vb0[4];
#pragma unroll
  for (int j2 = 0; j2 < 4; ++j2)
    vb0[j2] = *(const bf16x8*)(vg + (j2 * 16 + l15) * VTP_ + quad * 8);

  float sum[4] = {0.f, 0.f, 0.f, 0.f};
  f32x4 o[4] = {};

  auto QK = [&](int jt) {
    const int cur = jt & 1, nxt = cur ^ 1;
    if (jt + 1 < 13) {
      int kn1 = (jt + 1) * 16 + l15; if (kn1 > N_ - 1) kn1 = N_ - 1;
      const bf16* kp = kb + kn1 * HD_ + quad * 8;
      pk0[nxt] = *(const bf16x8*)(kp);
      pk1[nxt] = *(const bf16x8*)(kp + 32);
    }
    const int kn = jt * 16 + l15;    // <= 207 < RPT_, no clamp needed
    float rbv[4];
#pragma unroll
    for (int r2 = 0; r2 < 4; ++r2)
      rbv[r2] = (float)rpbT[((size_t)h * N_ + rn4[r2]) * RPT_ + kn];
    f32x4 s = {0.f, 0.f, 0.f, 0.f};
    __builtin_amdgcn_s_setprio(1);
    s = __builtin_amdgcn_mfma_f32_16x16x32_bf16(aq0, pk0[cur], s, 0, 0, 0);
    s = __builtin_amdgcn_mfma_f32_16x16x32_bf16(aq1, pk1[cur], s, 0, 0, 0);
    __builtin_amdgcn_s_setprio(0);
#pragma unroll
    for (int r = 0; r < 4; ++r) {
      // maskless: pad cols carry rpbT=-30000 -> exp underflows to exactly 0
      float p = __expf(s[r] + rbv[r]);
      bf16 pb = (bf16)p;
      s_lds[(w * 16 + quad * 4 + r) * SW + jt * 16 + l15] = pb;
      sum[r] += (float)pb;
    }
  };

  auto PV = [&](int kk) {
    bf16x8 ap = *(const bf16x8*)(&s_lds[(w * 16 + l15) * SW + kk * 32 + quad * 8]);
    __builtin_amdgcn_s_setprio(1);
#pragma unroll
    for (int j2 = 0; j2 < 4; ++j2)
      o[j2] = __builtin_amdgcn_mfma_f32_16x16x32_bf16(ap, vb0[j2], o[j2], 0, 0, 0);
    __builtin_amdgcn_s_setprio(0);
  };

#pragma unroll
  for (int jtp = 0; jtp < 6; ++jtp) {
    QK(2 * jtp);
    QK(2 * jtp + 1);
    PV(jtp);
    // prefetch V for kk=jtp+1; WAR-safe: issued after PV MFMAs
#pragma unroll
    for (int j2 = 0; j2 < 4; ++j2)
      vb0[j2] = *(const bf16x8*)(vg + (j2 * 16 + l15) * VTP_ + (jtp + 1) * 32 + quad * 8);
  }
  QK(12);
  // PV tail (kk=6): P cols 192..207 live (197..207 exact 0); cols 208..223 don't
  // exist -> zero the A-frag for quad>=2 (their k-slots contribute exactly 0).
  {
    bf16x8 ap = *(const bf16x8*)(&s_lds[(w * 16 + l15) * SW + 192 + (quad & 1) * 8]);
    bf16x8 zero = {};
    if (quad >= 2) ap = zero;
    __builtin_amdgcn_s_setprio(1);
#pragma unroll
    for (int j2 = 0; j2 < 4; ++j2)
      o[j2] = __builtin_amdgcn_mfma_f32_16x16x32_bf16(ap, vb0[j2], o[j2], 0, 0, 0);
    __builtin_amdgcn_s_setprio(0);
  }

  // row-sum reduce (within quad-groups) and normalize at store
#pragma unroll
  for (int r = 0; r < 4; ++r) {
    sum[r] += __shfl_xor(sum[r], 1);
    sum[r] += __shfl_xor(sum[r], 2);
    sum[r] += __shfl_xor(sum[r], 4);
    sum[r] += __shfl_xor(sum[r], 8);
  }
  float inv[4];
#pragma unroll
  for (int r = 0; r < 4; ++r) inv[r] = 1.0f / fmaxf(sum[r], 1e-20f);

#pragma unroll
  for (int j2 = 0; j2 < 4; ++j2) {
#pragma unroll
    for (int r = 0; r < 4; ++r) {
      int row = qt * 64 + w * 16 + quad * 4 + r;
      int hd = j2 * 16 + l15;
      if (row < N_)
        out[((size_t)b * N_ + row) * C_ + h * HD_ + hd] = (bf16)(o[j2][r] * inv[r]);
    }
  }
}

// ---------------- launch ----------------
extern "C" void kernel_launch(void* const* d_in, const int* in_sizes, int n_in,
                              void* d_out, int out_size, void* d_ws, size_t ws_size,
                              hipStream_t stream)
{
  const float* x      = (const float*)d_in[0];
  const float* qkv_w  = (const float*)d_in[1];
  const float* q_bias = (const float*)d_in[2];
  const float* v_bias = (const float*)d_in[3];
  const float* q_la   = (const float*)d_in[4];
  const float* q_lb   = (const float*)d_in[5];
  const float* k_la   = (const float*)d_in[6];
  const float* k_lb   = (const float*)d_in[7];
  const float* v_la   = (const float*)d_in[8];
  const float* v_lb   = (const float*)d_in[9];
  const float* rpt    = (const float*)d_in[10];
  const float* proj_w = (const float*)d_in[11];
  const float* proj_b = (const float*)d_in[12];
  const int*   rpi    = (const int*)d_in[13];
  float* out = (float*)d_out;

  char* ws = (char*)d_ws;
  // layout (16B-aligned); xbf dead after gemm<0>, reused as aout
  bf16*  xbf   = (bf16*)(ws);                         // 19,365,888 B
  bf16*  aout  = (bf16*)(ws);                         // alias
  bf16*  weff  = (bf16*)(ws + 19365888);              //  3,538,944 B
  float* biasf = (float*)(ws + 22904832);             //      9,216 B
  bf16*  pwbf  = (bf16*)(ws + 22914048);              //  1,179,648 B
  bf16*  qbuf  = (bf16*)(ws + 24093696);              // 19,365,888 B
  bf16*  kbuf  = (bf16*)(ws + 43459584);              // 19,365,888 B
  bf16*  vbufT = (bf16*)(ws + 62825472);              // 19,660,800 (+128 slack)
  bf16*  rpbT  = (bf16*)(ws + 82486400);              // 983,424 (12*197*208*2)
  // total ws use ≈ 83.5 MB

  prep_kernel<<<13849, 256, 0, stream>>>(
      x, proj_w, qkv_w, q_bias, v_bias, q_la, q_lb, k_la, k_lb, v_la, v_lb,
      rpt, rpi, xbf, pwbf, weff, biasf, rpbT);

  gemm_bt<0, 128><<<dim3(18, 99), 512, 0, stream>>>(
      xbf, weff, biasf, nullptr, M_, 3 * C_, C_, qbuf, kbuf, vbufT);

  // flat 3072-block grid; XCD-chunked swizzle inside the kernel
  attn_kernel<<<dim3(3072), 256, 0, stream>>>(qbuf, kbuf, vbufT, rpbT, aout);

  gemm_bt<1, 128><<<dim3(6, 99), 512, 0, stream>>>(
      aout, pwbf, proj_b, out, M_, C_, C_, nullptr, nullptr, nullptr);
}

// Round 12
// 262.887 us; speedup vs baseline: 1.0373x; 1.0373x over previous
//
#include <hip/hip_runtime.h>

typedef __bf16 bf16;
typedef __attribute__((ext_vector_type(8))) __bf16 bf16x8;
typedef __attribute__((ext_vector_type(4))) __bf16 bf16x4;
typedef __attribute__((ext_vector_type(4))) float f32x4;

#define B_    64
#define N_    197
#define C_    768
#define H_    12
#define HD_   64
#define SCALE_ 0.125f
#define NM_   (N_*N_)         // 38809
#define M_    (B_*N_)         // 12608
#define VTP_  200             // vbufT row pad
#define RPT_  208             // rpbT row stride (cols 197..207 pre-poisoned to -30000)

#define GLL16(gptr, lptr) \
  __builtin_amdgcn_global_load_lds((const __attribute__((address_space(1))) unsigned int*)(gptr), \
                                   (__attribute__((address_space(3))) unsigned int*)(lptr), 16, 0, 0)

// ---------------- fused prep: cast x/proj_w, W_eff + bias, rpbT ----------------
// blocks [0,5016): cast; [5016,11928): weff; [11928,13849): rpbT
// rpbT layout [h][q-row n][k-col m], stride RPT_=208: cols [197,208) filled with
// -30000 so attn's QK loop needs NO column mask (exp underflows to exact 0).
__global__ __launch_bounds__(256) void prep_kernel(
    const float* __restrict__ x, const float* __restrict__ pw,
    const float* __restrict__ qkv_w, const float* __restrict__ q_bias, const float* __restrict__ v_bias,
    const float* __restrict__ qa, const float* __restrict__ qb,
    const float* __restrict__ ka, const float* __restrict__ kb,
    const float* __restrict__ va, const float* __restrict__ vb,
    const float* __restrict__ table, const int* __restrict__ rpi,
    bf16* __restrict__ xbf, bf16* __restrict__ pwbf,
    bf16* __restrict__ weff, float* __restrict__ biasf, bf16* __restrict__ rpbT)
{
  const int bid = blockIdx.x, tid = threadIdx.x;
  if (bid < 5016) {
    const size_t n1 = (size_t)M_ * C_;   // 9,682,944
    size_t i8 = ((size_t)bid * 256 + tid) * 8;
    const float* src; bf16* dst; size_t off;
    if (i8 < n1) { src = x;  dst = xbf;  off = i8; }
    else         { src = pw; dst = pwbf; off = i8 - n1; }
    float4 f0 = *(const float4*)(src + off);
    float4 f1 = *(const float4*)(src + off + 4);
    bf16x8 v8;
    v8[0] = (bf16)f0.x; v8[1] = (bf16)f0.y; v8[2] = (bf16)f0.z; v8[3] = (bf16)f0.w;
    v8[4] = (bf16)f1.x; v8[5] = (bf16)f1.y; v8[6] = (bf16)f1.z; v8[7] = (bf16)f1.w;
    *(bf16x8*)(dst + off) = v8;
  } else if (bid < 11928) {
    int idx = (bid - 5016) * 256 + tid;          // < 1,769,472 exact
    int d = idx / C_, c = idx - d * C_;
    int sel = d / C_, dd = d - sel * C_;
    const float* a  = (sel == 0) ? qa : (sel == 1) ? ka : va;
    const float* bw = (sel == 0) ? qb : (sel == 1) ? kb : vb;
    float acc = qkv_w[idx];
#pragma unroll
    for (int r = 0; r < 24; ++r)
      acc += bw[dd * 24 + r] * a[r * C_ + c];
    weff[idx] = (bf16)acc;
    if (c == 0)
      biasf[d] = (sel == 0) ? q_bias[dd] : (sel == 2) ? v_bias[dd] : 0.0f;
  } else {
    int idx = (bid - 11928) * 256 + tid;
    if (idx < H_ * N_ * RPT_) {
      int h = idx / (N_ * RPT_), rem = idx - h * (N_ * RPT_);
      int n = rem / RPT_, m = rem - n * RPT_;
      float v = (m < N_) ? table[rpi[n * N_ + m] * H_ + h] : -30000.0f;
      rpbT[((size_t)h * N_ + n) * RPT_ + m] = (bf16)v;   // unit-stride write
    }
  }
}

// ---------------- gemm_bt: QKV GEMM (MODE 0 only now) ----------------
// R10 winner, UNTOUCHED: BM=128, 8 waves, 32KB LDS, 32 waves/CU, packed bf16x4 v-stores,
// m204 bijective XCD-chunked swizzle.
template<int MODE, int BM>
__global__ __launch_bounds__(512, 8) void gemm_bt(
    const bf16* __restrict__ A, const bf16* __restrict__ Bw,
    const float* __restrict__ biasp,
    float* __restrict__ Coutf, int M, int Nn, int K,
    bf16* __restrict__ qo, bf16* __restrict__ ko, bf16* __restrict__ vo)
{
  __shared__ __align__(16) bf16 As[BM * 64];
  __shared__ __align__(16) bf16 Bs[128 * 64];
  const int tid = threadIdx.x;
  const int lane = tid & 63, w = tid >> 6;          // 8 waves
  const int l15 = lane & 15, quad = lane >> 4;
  const int wm = (w & 1) * 64;                      // M half (64 rows)
  const int wn = (w >> 1) * 32;                     // N quarter (32 cols)
  constexpr int NF = 2;                             // B-fragments per wave

  // m204 bijective XCD-chunked swizzle
  const int ntx = gridDim.x;
  const int nwg = ntx * gridDim.y;
  const int orig = blockIdx.y * ntx + blockIdx.x;
  const int xcd = orig & 7, hi = orig >> 3;
  const int qq = nwg >> 3, rr = nwg & 7;
  const int wg = (xcd < rr ? xcd * (qq + 1) : rr * (qq + 1) + (xcd - rr) * qq) + hi;
  const int rowB0 = (wg % ntx) * 128;   // N-tile (fastest-varying)
  const int rowA0 = (wg / ntx) * BM;    // M-tile

  f32x4 acc[4][NF] = {};

  for (int kt = 0; kt < K; kt += 64) {
#pragma unroll
    for (int i = 0; i < BM / 64; ++i) {            // A: BM x 64 tile
      int lin = i * 512 + tid;
      int r  = lin >> 3;                           // 0..BM-1
      int cb = lin & 7;                            // LDS column block
      int csw = ((cb ^ (r & 7)) << 3);             // swizzled global column (elems)
      int ga = rowA0 + r; if (ga > M - 1) ga = M - 1;
      GLL16(A + (size_t)ga * K + kt + csw, &As[lin * 8]);
    }
#pragma unroll
    for (int i = 0; i < 2; ++i) {                  // B: 128 x 64 tile
      int lin = i * 512 + tid;
      int r  = lin >> 3;
      int cb = lin & 7;
      int csw = ((cb ^ (r & 7)) << 3);
      int gb = rowB0 + r; if (gb > Nn - 1) gb = Nn - 1;
      GLL16(Bw + (size_t)gb * K + kt + csw, &Bs[lin * 8]);
    }
    __syncthreads();
#pragma unroll
    for (int ks = 0; ks < 2; ++ks) {
      const int cb = ks * 4 + quad;                // k-block 0..7
      const int sw = (cb ^ (l15 & 7)) << 3;
      bf16x8 af[4], bfr[NF];
#pragma unroll
      for (int i = 0; i < 4; ++i)
        af[i] = *(const bf16x8*)(&As[(wm + i * 16 + l15) * 64 + sw]);
#pragma unroll
      for (int j = 0; j < NF; ++j)
        bfr[j] = *(const bf16x8*)(&Bs[(wn + j * 16 + l15) * 64 + sw]);
#pragma unroll
      for (int i = 0; i < 4; ++i)
#pragma unroll
        for (int j = 0; j < NF; ++j)
          acc[i][j] = __builtin_amdgcn_mfma_f32_16x16x32_bf16(af[i], bfr[j], acc[i][j], 0, 0, 0);
    }
    __syncthreads();
  }

#pragma unroll
  for (int i = 0; i < 4; ++i) {
#pragma unroll
    for (int j = 0; j < NF; ++j) {
      const int m0 = rowA0 + wm + i * 16 + quad * 4;
      const int d  = rowB0 + wn + j * 16 + l15;
      const float bias = biasp[d];
      if (MODE == 0) {
        const int sel = d / C_, dd = d - sel * C_;
        const int h = dd >> 6, hd = dd & 63;
        if (sel == 2) {
          // v transposed: lane's 4 r-values = consecutive n for fixed (b,h,hd) row
          int b0 = m0 / N_, n0 = m0 - b0 * N_;
          if (m0 + 3 < M && n0 + 3 < N_) {
            bf16x4 pv;
#pragma unroll
            for (int r = 0; r < 4; ++r) pv[r] = (bf16)(acc[i][j][r] + bias);
            *(bf16x4*)(vo + (((size_t)b0 * H_ + h) * HD_ + hd) * VTP_ + n0) = pv;
          } else {
#pragma unroll
            for (int r = 0; r < 4; ++r) {
              int m = m0 + r; if (m >= M) continue;
              int b = m / N_, n = m - b * N_;
              vo[(((size_t)b * H_ + h) * HD_ + hd) * VTP_ + n] = (bf16)(acc[i][j][r] + bias);
            }
          }
        } else {
#pragma unroll
          for (int r = 0; r < 4; ++r) {
            int m = m0 + r; if (m >= M) continue;
            int b = m / N_, n = m - b * N_;
            float v = acc[i][j][r] + bias;
            if (sel == 0)
              qo[(((size_t)b * H_ + h) * N_ + n) * HD_ + hd] = (bf16)(v * SCALE_);
            else
              ko[(((size_t)b * H_ + h) * N_ + n) * HD_ + hd] = (bf16)v;
          }
        }
      } else {
#pragma unroll
        for (int r = 0; r < 4; ++r) {
          int m = m0 + r; if (m >= M) continue;
          Coutf[(size_t)m * Nn + d] = acc[i][j][r] + bias;
        }
      }
    }
  }
}

// ---------------- gemm_proj: proj GEMM, 64x128 tile, 256 thr, machine-fill fix ----------------
// R12: old proj grid was 594 blocks of 512 thr = 2.3 blocks/CU avg vs 4/CU capacity ->
// ~58% machine fill for its whole duration (the R5 law violated). This kernel: 64x128
// tile, 4 waves of 32x64 (acc 2x4), 24KB LDS -> grid (6,197)=1182 blocks (M=197*64
// exactly, zero tail), 6 blocks/CU capacity, ~4.6/CU fill. Same staging/swizzle/
// barrier template, same m204 XCD swizzle. C[m,d] = acc + bias -> f32.
__global__ __launch_bounds__(256, 6) void gemm_proj(
    const bf16* __restrict__ A, const bf16* __restrict__ Bw,
    const float* __restrict__ biasp, float* __restrict__ Coutf,
    int M, int Nn, int K)
{
  __shared__ __align__(16) bf16 As[64 * 64];     //  8 KiB
  __shared__ __align__(16) bf16 Bs[128 * 64];    // 16 KiB
  const int tid = threadIdx.x;
  const int lane = tid & 63, w = tid >> 6;       // 4 waves
  const int l15 = lane & 15, quad = lane >> 4;
  const int wm = (w & 1) * 32;                   // M half (32 rows)
  const int wn = (w >> 1) * 64;                  // N half (64 cols)

  // m204 bijective XCD-chunked swizzle (nwg = 6*197 = 1182)
  const int ntx = gridDim.x;
  const int nwg = ntx * gridDim.y;
  const int orig = blockIdx.y * ntx + blockIdx.x;
  const int xcd = orig & 7, hi = orig >> 3;
  const int qq = nwg >> 3, rr = nwg & 7;
  const int wg = (xcd < rr ? xcd * (qq + 1) : rr * (qq + 1) + (xcd - rr) * qq) + hi;
  const int rowB0 = (wg % ntx) * 128;   // N-tile (fastest-varying)
  const int rowA0 = (wg / ntx) * 64;    // M-tile (divides exactly: 197*64 = 12608)

  f32x4 acc[2][4] = {};

  for (int kt = 0; kt < K; kt += 64) {
#pragma unroll
    for (int i = 0; i < 2; ++i) {                // A: 64 x 64 tile (512 chunks)
      int lin = i * 256 + tid;
      int r  = lin >> 3;                         // 0..63
      int cb = lin & 7;
      int csw = ((cb ^ (r & 7)) << 3);
      int ga = rowA0 + r; if (ga > M - 1) ga = M - 1;
      GLL16(A + (size_t)ga * K + kt + csw, &As[lin * 8]);
    }
#pragma unroll
    for (int i = 0; i < 4; ++i) {                // B: 128 x 64 tile (1024 chunks)
      int lin = i * 256 + tid;
      int r  = lin >> 3;                         // 0..127
      int cb = lin & 7;
      int csw = ((cb ^ (r & 7)) << 3);
      int gb = rowB0 + r; if (gb > Nn - 1) gb = Nn - 1;
      GLL16(Bw + (size_t)gb * K + kt + csw, &Bs[lin * 8]);
    }
    __syncthreads();
#pragma unroll
    for (int ks = 0; ks < 2; ++ks) {
      const int cb = ks * 4 + quad;
      const int sw = (cb ^ (l15 & 7)) << 3;
      bf16x8 af[2], bfr[4];
#pragma unroll
      for (int i = 0; i < 2; ++i)
        af[i] = *(const bf16x8*)(&As[(wm + i * 16 + l15) * 64 + sw]);
#pragma unroll
      for (int j = 0; j < 4; ++j)
        bfr[j] = *(const bf16x8*)(&Bs[(wn + j * 16 + l15) * 64 + sw]);
#pragma unroll
      for (int i = 0; i < 2; ++i)
#pragma unroll
        for (int j = 0; j < 4; ++j)
          acc[i][j] = __builtin_amdgcn_mfma_f32_16x16x32_bf16(af[i], bfr[j], acc[i][j], 0, 0, 0);
    }
    __syncthreads();
  }

#pragma unroll
  for (int i = 0; i < 2; ++i) {
#pragma unroll
    for (int j = 0; j < 4; ++j) {
      const int m0 = rowA0 + wm + i * 16 + quad * 4;
      const int d  = rowB0 + wn + j * 16 + l15;
      const float bias = biasp[d];
#pragma unroll
      for (int r = 0; r < 4; ++r) {
        int m = m0 + r; if (m >= M) continue;
        Coutf[(size_t)m * Nn + d] = acc[i][j][r] + bias;
      }
    }
  }
}

// ---------------- attention: barrier-free, max-free softmax, interleaved QK/PV ----------------
// R11 config (kept): SW=208 -> 6 blocks/CU; maskless QK via pre-poisoned rpbT;
// PV tail zeroes quad>=2 A-frag. R10<->R11 measured equal within +-10us session noise.
#define SW 208   // P row stride (bf16 elems); PV consumes cols 0..207
__global__ __launch_bounds__(256) void attn_kernel(
    const bf16* __restrict__ q, const bf16* __restrict__ k, const bf16* __restrict__ vT_g,
    const bf16* __restrict__ rpbT, bf16* __restrict__ out)
{
  __shared__ __align__(16) bf16 s_lds[64 * SW];   // P tile (each wave owns its 16 rows)

  const int tid = threadIdx.x;
  const int lane = tid & 63, w = tid >> 6;
  const int l15 = lane & 15, quad = lane >> 4;
  // XCD-chunked bijection (3072 = 8 XCDs x 384): same-(h,b) blocks co-located.
  const int lid = blockIdx.x;
  const int wg = (lid & 7) * 384 + (lid >> 3);
  const int qt = wg & 3;
  const int hb = wg >> 2;
  const int h = hb % H_;
  const int b = hb / H_;
  const size_t bh = ((size_t)b * H_ + h) * N_ * HD_;
  const bf16* qb = q + bh;
  const bf16* kb = k + bh;
  const bf16* vg = vT_g + ((size_t)b * H_ + h) * HD_ * VTP_;

  const int row0 = qt * 64 + w * 16;
  int qm = row0 + l15; if (qm > N_ - 1) qm = N_ - 1;
  bf16x8 aq0 = *(const bf16x8*)(qb + qm * HD_ + quad * 8);
  bf16x8 aq1 = *(const bf16x8*)(qb + qm * HD_ + 32 + quad * 8);

  // hoisted row indices for rpbT (clamped; dead rows' outputs discarded at store)
  int rn4[4];
#pragma unroll
  for (int r2 = 0; r2 < 4; ++r2) {
    int rn = row0 + quad * 4 + r2; if (rn > N_ - 1) rn = N_ - 1;
    rn4[r2] = rn;
  }

  // 2-deep K pipeline: slot jt&1 computes, slot (jt+1)&1 prefetches
  bf16x8 pk0[2], pk1[2];
  {
    const bf16* kp0 = kb + l15 * HD_ + quad * 8;   // jt=0: kn = l15 (<197, no clamp)
    pk0[0] = *(const bf16x8*)(kp0);
    pk1[0] = *(const bf16x8*)(kp0 + 32);
  }
  // 1-deep V: fragments for current kk (loads fly under the 2 preceding QK iters)
  bf16x8 vb0[4];
#pragma unroll
  for (int j2 = 0; j2 < 4; ++j2)
    vb0[j2] = *(const bf16x8*)(vg + (j2 * 16 + l15) * VTP_ + quad * 8);

  float sum[4] = {0.f, 0.f, 0.f, 0.f};
  f32x4 o[4] = {};

  auto QK = [&](int jt) {
    const int cur = jt & 1, nxt = cur ^ 1;
    if (jt + 1 < 13) {
      int kn1 = (jt + 1) * 16 + l15; if (kn1 > N_ - 1) kn1 = N_ - 1;
      const bf16* kp = kb + kn1 * HD_ + quad * 8;
      pk0[nxt] = *(const bf16x8*)(kp);
      pk1[nxt] = *(const bf16x8*)(kp + 32);
    }
    const int kn = jt * 16 + l15;    // <= 207 < RPT_, no clamp needed
    float rbv[4];
#pragma unroll
    for (int r2 = 0; r2 < 4; ++r2)
      rbv[r2] = (float)rpbT[((size_t)h * N_ + rn4[r2]) * RPT_ + kn];
    f32x4 s = {0.f, 0.f, 0.f, 0.f};
    __builtin_amdgcn_s_setprio(1);
    s = __builtin_amdgcn_mfma_f32_16x16x32_bf16(aq0, pk0[cur], s, 0, 0, 0);
    s = __builtin_amdgcn_mfma_f32_16x16x32_bf16(aq1, pk1[cur], s, 0, 0, 0);
    __builtin_amdgcn_s_setprio(0);
#pragma unroll
    for (int r = 0; r < 4; ++r) {
      // maskless: pad cols carry rpbT=-30000 -> exp underflows to exactly 0
      float p = __expf(s[r] + rbv[r]);
      bf16 pb = (bf16)p;
      s_lds[(w * 16 + quad * 4 + r) * SW + jt * 16 + l15] = pb;
      sum[r] += (float)pb;
    }
  };

  auto PV = [&](int kk) {
    bf16x8 ap = *(const bf16x8*)(&s_lds[(w * 16 + l15) * SW + kk * 32 + quad * 8]);
    __builtin_amdgcn_s_setprio(1);
#pragma unroll
    for (int j2 = 0; j2 < 4; ++j2)
      o[j2] = __builtin_amdgcn_mfma_f32_16x16x32_bf16(ap, vb0[j2], o[j2], 0, 0, 0);
    __builtin_amdgcn_s_setprio(0);
  };

#pragma unroll
  for (int jtp = 0; jtp < 6; ++jtp) {
    QK(2 * jtp);
    QK(2 * jtp + 1);
    PV(jtp);
    // prefetch V for kk=jtp+1; WAR-safe: issued after PV MFMAs
#pragma unroll
    for (int j2 = 0; j2 < 4; ++j2)
      vb0[j2] = *(const bf16x8*)(vg + (j2 * 16 + l15) * VTP_ + (jtp + 1) * 32 + quad * 8);
  }
  QK(12);
  // PV tail (kk=6): P cols 192..207 live (197..207 exact 0); cols 208..223 don't
  // exist -> zero the A-frag for quad>=2 (their k-slots contribute exactly 0).
  {
    bf16x8 ap = *(const bf16x8*)(&s_lds[(w * 16 + l15) * SW + 192 + (quad & 1) * 8]);
    bf16x8 zero = {};
    if (quad >= 2) ap = zero;
    __builtin_amdgcn_s_setprio(1);
#pragma unroll
    for (int j2 = 0; j2 < 4; ++j2)
      o[j2] = __builtin_amdgcn_mfma_f32_16x16x32_bf16(ap, vb0[j2], o[j2], 0, 0, 0);
    __builtin_amdgcn_s_setprio(0);
  }

  // row-sum reduce (within quad-groups) and normalize at store
#pragma unroll
  for (int r = 0; r < 4; ++r) {
    sum[r] += __shfl_xor(sum[r], 1);
    sum[r] += __shfl_xor(sum[r], 2);
    sum[r] += __shfl_xor(sum[r], 4);
    sum[r] += __shfl_xor(sum[r], 8);
  }
  float inv[4];
#pragma unroll
  for (int r = 0; r < 4; ++r) inv[r] = 1.0f / fmaxf(sum[r], 1e-20f);

#pragma unroll
  for (int j2 = 0; j2 < 4; ++j2) {
#pragma unroll
    for (int r = 0; r < 4; ++r) {
      int row = qt * 64 + w * 16 + quad * 4 + r;
      int hd = j2 * 16 + l15;
      if (row < N_)
        out[((size_t)b * N_ + row) * C_ + h * HD_ + hd] = (bf16)(o[j2][r] * inv[r]);
    }
  }
}

// ---------------- launch ----------------
extern "C" void kernel_launch(void* const* d_in, const int* in_sizes, int n_in,
                              void* d_out, int out_size, void* d_ws, size_t ws_size,
                              hipStream_t stream)
{
  const float* x      = (const float*)d_in[0];
  const float* qkv_w  = (const float*)d_in[1];
  const float* q_bias = (const float*)d_in[2];
  const float* v_bias = (const float*)d_in[3];
  const float* q_la   = (const float*)d_in[4];
  const float* q_lb   = (const float*)d_in[5];
  const float* k_la   = (const float*)d_in[6];
  const float* k_lb   = (const float*)d_in[7];
  const float* v_la   = (const float*)d_in[8];
  const float* v_lb   = (const float*)d_in[9];
  const float* rpt    = (const float*)d_in[10];
  const float* proj_w = (const float*)d_in[11];
  const float* proj_b = (const float*)d_in[12];
  const int*   rpi    = (const int*)d_in[13];
  float* out = (float*)d_out;

  char* ws = (char*)d_ws;
  // layout (16B-aligned); xbf dead after gemm<0>, reused as aout
  bf16*  xbf   = (bf16*)(ws);                         // 19,365,888 B
  bf16*  aout  = (bf16*)(ws);                         // alias
  bf16*  weff  = (bf16*)(ws + 19365888);              //  3,538,944 B
  float* biasf = (float*)(ws + 22904832);             //      9,216 B
  bf16*  pwbf  = (bf16*)(ws + 22914048);              //  1,179,648 B
  bf16*  qbuf  = (bf16*)(ws + 24093696);              // 19,365,888 B
  bf16*  kbuf  = (bf16*)(ws + 43459584);              // 19,365,888 B
  bf16*  vbufT = (bf16*)(ws + 62825472);              // 19,660,800 (+128 slack)
  bf16*  rpbT  = (bf16*)(ws + 82486400);              // 983,424 (12*197*208*2)
  // total ws use ≈ 83.5 MB

  prep_kernel<<<13849, 256, 0, stream>>>(
      x, proj_w, qkv_w, q_bias, v_bias, q_la, q_lb, k_la, k_lb, v_la, v_lb,
      rpt, rpi, xbf, pwbf, weff, biasf, rpbT);

  gemm_bt<0, 128><<<dim3(18, 99), 512, 0, stream>>>(
      xbf, weff, biasf, nullptr, M_, 3 * C_, C_, qbuf, kbuf, vbufT);

  // flat 3072-block grid; XCD-chunked swizzle inside the kernel
  attn_kernel<<<dim3(3072), 256, 0, stream>>>(qbuf, kbuf, vbufT, rpbT, aout);

  // machine-fill proj GEMM: 1182 blocks of 256 thr (was 594 of 512 -> 58% fill)
  gemm_proj<<<dim3(6, 197), 256, 0, stream>>>(
      aout, pwbf, proj_b, out, M_, C_, C_);
}